// Round 2
// baseline (223.894 us; speedup 1.0000x reference)
//
#include <hip/hip_runtime.h>
#include <hip/hip_bf16.h>

#define BN 4
#define CN 64
#define ON 64
#define HN 128
#define WN 128
#define HWN (HN*WN)
#define NT 9

typedef __attribute__((ext_vector_type(8))) short bf16x8;
typedef __attribute__((ext_vector_type(4))) float floatx4;

static __device__ __forceinline__ unsigned short f2bf(float f) {
    unsigned int u = __builtin_bit_cast(unsigned int, f);
    u += 0x7fffu + ((u >> 16) & 1u);   // RNE
    return (unsigned short)(u >> 16);
}

// ---------------------------------------------------------------------------
// Tiny prep: transpose w_conv (O,C,3,3) fp32 -> bf16 wbf[n][o][c].
// ---------------------------------------------------------------------------
__global__ __launch_bounds__(256) void prep_wbf(
    const float* __restrict__ w_conv, unsigned short* __restrict__ wbf)
{
    int p = blockIdx.x * 256 + threadIdx.x;
    if (p < ON*CN*NT) {
        int o   = p / (CN*NT);
        int rem = p - o*(CN*NT);
        int c   = rem / NT;
        int n   = rem - c*NT;
        wbf[(n*ON + o)*CN + c] = f2bf(w_conv[p]);
    }
}

// ---------------------------------------------------------------------------
// Fused kernel: per-block (64 px of one row):
//   phase 0: 1-channel offset conv (wave g covers channels g*16..g*16+15)
//   phase 1: homography -> 9 tap descriptors per pixel (addresses + weights)
//   phase 2: 9x { bilinear-gather 64px x 64c bf16 tile -> LDS, MFMA vs wbf }
// Block swizzle: contiguous 128-block chunks per XCD -> 2.1 MB slab fits L2.
// ---------------------------------------------------------------------------
#define LDS_BYTES 27648   // tapA 9216 | tapW 9216 | sT 9216 (64 x 72 bf16)

__global__ __launch_bounds__(256) void deform_fused(
    const float* __restrict__ x, const float* __restrict__ w_off,
    const unsigned short* __restrict__ wbf,
    const float* __restrict__ P, const float* __restrict__ d,
    const float* __restrict__ Pinv, float* __restrict__ out)
{
    __shared__ char lds[LDS_BYTES];
    int4*   tapA = (int4*)lds;                              // [576]
    float4* tapW = (float4*)(lds + 9216);                   // [576]
    unsigned short* sT = (unsigned short*)(lds + 18432);    // [64][72]
    // prep-phase aliases inside the sT region (dead before first sT write):
    float* swoff    = (float*)(lds + 18432);                // [576]
    float* partials = (float*)(lds + 18432 + 2304);         // [4][64]
    float* HomLDS   = (float*)(lds + 18432 + 3328);         // [64][9]

    const int tid  = threadIdx.x;
    const int lane = tid & 63;
    const int g    = tid >> 6;           // wave id 0..3

    // XCD-contiguity swizzle: XCD k gets blocks [k*128, (k+1)*128) = 64 rows.
    const int nb    = ((blockIdx.x & 7) << 7) | (blockIdx.x >> 3);
    const int pbase = nb * 64;
    const int w0    = pbase & (WN-1);
    const int hi    = (pbase >> 7) & (HN-1);
    const int bi    = pbase >> 14;
    const float* xb = x + (size_t)bi * CN * HWN;

    // ---- load offset-conv weights
    for (int i = tid; i < CN*NT; i += 256) swoff[i] = w_off[i];
    __syncthreads();

    // ---- phase 0: offset conv. lane = pixel, wave g = channels g*16..+15
    {
        float part = 0.f;
        #pragma unroll
        for (int ky = 0; ky < 3; ++ky) {
            int yy = hi + ky - 1;
            bool vy = (yy >= 0) & (yy < HN);
            #pragma unroll
            for (int kx = 0; kx < 3; ++kx) {
                int xx = w0 + lane + kx - 1;
                bool v = vy & (xx >= 0) & (xx < WN);
                int a = yy*WN + xx;
                #pragma unroll
                for (int j = 0; j < 16; ++j) {
                    int c = g*16 + j;
                    float xv = v ? xb[c*HWN + a] : 0.f;
                    part += xv * swoff[c*NT + ky*3 + kx];
                }
            }
        }
        partials[g*64 + lane] = part;
    }
    __syncthreads();

    // ---- phase 1a: per-pixel homography (threads 0..63)
    if (tid < 64) {
        float raw = partials[tid] + partials[64+tid] + partials[128+tid] + partials[192+tid];
        float lw = fminf(fmaxf(raw + 0.5f, 0.f), 1.f);
        float pw0 = exp2f(lw * log2f(d[0]));
        float pw1 = exp2f(lw * log2f(d[1]));
        float pw2 = exp2f(lw * log2f(d[2]));
        #pragma unroll
        for (int i = 0; i < 3; ++i)
            #pragma unroll
            for (int j = 0; j < 3; ++j)
                HomLDS[tid*9 + i*3 + j] = P[i*3+0]*pw0*Pinv[0+j]
                                        + P[i*3+1]*pw1*Pinv[3+j]
                                        + P[i*3+2]*pw2*Pinv[6+j];
    }
    __syncthreads();

    // ---- phase 1b: tap descriptors (576 = 64 px x 9 taps)
    for (int e = tid; e < 64*NT; e += 256) {
        int pix = e / NT, n = e - pix*NT;
        const float* Hm = &HomLDS[pix*9];
        float fx0 = (float)(n % 3) - 1.f;
        float fy0 = (float)(n / 3) - 1.f;
        float qx = Hm[0]*fx0 + Hm[1]*fy0 + Hm[2];
        float qy = Hm[3]*fx0 + Hm[4]*fy0 + Hm[5];
        float qz = Hm[6]*fx0 + Hm[7]*fy0 + Hm[8];
        float ri = 1.f / qz;
        float px = (float)(w0 + pix) + qx*ri;
        float py = (float)hi + qy*ri;
        float x0f = floorf(px), y0f = floorf(py);
        float fx = px - x0f,    fy = py - y0f;
        int ix0 = (int)x0f, iy0 = (int)y0f;
        int ix1 = ix0 + 1,  iy1 = iy0 + 1;
        float vx0 = (ix0 >= 0 && ix0 < WN) ? 1.f : 0.f;
        float vx1 = (ix1 >= 0 && ix1 < WN) ? 1.f : 0.f;
        float vy0 = (iy0 >= 0 && iy0 < HN) ? 1.f : 0.f;
        float vy1 = (iy1 >= 0 && iy1 < HN) ? 1.f : 0.f;
        int x0c = min(max(ix0,0),WN-1), x1c = min(max(ix1,0),WN-1);
        int y0c = min(max(iy0,0),HN-1), y1c = min(max(iy1,0),HN-1);
        int4   ta = make_int4(y0c*WN+x0c, y0c*WN+x1c, y1c*WN+x0c, y1c*WN+x1c);
        float4 tw = make_float4((1.f-fy)*(1.f-fx)*vy0*vx0, (1.f-fy)*fx*vy0*vx1,
                                fy*(1.f-fx)*vy1*vx0,       fy*fx*vy1*vx1);
        // NOTE: tapA/tapW live in lds[0..18432) — does NOT alias prep scratch
        tapA[e] = ta;
        tapW[e] = tw;
    }

    const int q    = lane >> 4;          // quad within wave
    const int m15  = lane & 15;
    const int mpix = g*16 + m15;

    floatx4 acc[4];
    #pragma unroll
    for (int f = 0; f < 4; ++f) acc[f] = (floatx4){0.f,0.f,0.f,0.f};

    for (int n = 0; n < NT; ++n) {
        __syncthreads();                 // taps ready / sT safe to overwrite
        {
            // gather: lanes = pixels (coalesced), wave g covers c=g*16..+15
            int pix = lane;
            int4   ta = tapA[pix*NT + n];
            float4 tw = tapW[pix*NT + n];
            const float* pc = xb + (g*16)*HWN;
            unsigned int packed[8];
            #pragma unroll
            for (int jj = 0; jj < 8; ++jj) {
                const float* p0 = pc + (2*jj)*HWN;
                float v0 = tw.x*p0[ta.x] + tw.y*p0[ta.y]
                         + tw.z*p0[ta.z] + tw.w*p0[ta.w];
                const float* p1 = p0 + HWN;
                float v1 = tw.x*p1[ta.x] + tw.y*p1[ta.y]
                         + tw.z*p1[ta.z] + tw.w*p1[ta.w];
                packed[jj] = (unsigned int)f2bf(v0)
                           | ((unsigned int)f2bf(v1) << 16);
            }
            int4* dst = (int4*)&sT[pix*72 + g*16];   // 16B-aligned (72*2=144)
            dst[0] = make_int4(packed[0],packed[1],packed[2],packed[3]);
            dst[1] = make_int4(packed[4],packed[5],packed[6],packed[7]);
        }
        __syncthreads();

        // MFMA: wave g computes pix rows [g*16, g*16+16) x all 64 o
        #pragma unroll
        for (int k0 = 0; k0 < 64; k0 += 32) {
            bf16x8 a = *(const bf16x8*)&sT[mpix*72 + k0 + q*8];
            #pragma unroll
            for (int f = 0; f < 4; ++f) {
                bf16x8 bfr = *(const bf16x8*)&wbf[((size_t)(n*ON + f*16 + m15))*CN + k0 + q*8];
                acc[f] = __builtin_amdgcn_mfma_f32_16x16x32_bf16(a, bfr, acc[f], 0, 0, 0);
            }
        }
    }

    // ---- epilogue: transpose through LDS for coalesced stores
    __syncthreads();
    float* tr = (float*)lds;             // [64 o][72 px] over tap region (dead)
    #pragma unroll
    for (int f = 0; f < 4; ++f) {
        int o = f*16 + m15;
        #pragma unroll
        for (int r = 0; r < 4; ++r) {
            int pix = g*16 + q*4 + r;    // C/D layout: row=(lane>>4)*4+reg
            tr[o*72 + pix] = acc[f][r];
        }
    }
    __syncthreads();
    float* ob = out + (((size_t)bi*ON)*HN + hi)*WN + w0;
    #pragma unroll
    for (int j = 0; j < 16; ++j) {
        int o = g*16 + j;
        ob[(size_t)o*HWN + lane] = tr[o*72 + lane];
    }
}

// ---------------------------------------------------------------------------
extern "C" void kernel_launch(void* const* d_in, const int* in_sizes, int n_in,
                              void* d_out, int out_size, void* d_ws, size_t ws_size,
                              hipStream_t stream) {
    const float* x      = (const float*)d_in[0];
    const float* w_off  = (const float*)d_in[1];
    const float* w_conv = (const float*)d_in[2];
    const float* P      = (const float*)d_in[3];
    const float* d      = (const float*)d_in[4];
    const float* Pinv   = (const float*)d_in[5];
    float* out = (float*)d_out;

    unsigned short* wbf = (unsigned short*)d_ws;   // 73728 B

    prep_wbf<<<144, 256, 0, stream>>>(w_conv, wbf);
    deform_fused<<<1024, 256, 0, stream>>>(x, w_off, wbf, P, d, Pinv, out);
}

// Round 4
// 205.301 us; speedup vs baseline: 1.0906x; 1.0906x over previous
//
#include <hip/hip_runtime.h>
#include <hip/hip_bf16.h>

#define BN 4
#define CN 64
#define ON 64
#define HN 128
#define WN 128
#define HWN (HN*WN)
#define NT 9

typedef __attribute__((ext_vector_type(8))) short bf16x8;
typedef __attribute__((ext_vector_type(4))) float floatx4;

static __device__ __forceinline__ unsigned short f2bf(float f) {
    unsigned int u = __builtin_bit_cast(unsigned int, f);
    u += 0x7fffu + ((u >> 16) & 1u);   // RNE
    return (unsigned short)(u >> 16);
}

// ---------------------------------------------------------------------------
// Tiny prep: transpose w_conv (O,C,3,3) fp32 -> bf16 wbf[n][o][c].
// ---------------------------------------------------------------------------
__global__ __launch_bounds__(256) void prep_wbf(
    const float* __restrict__ w_conv, unsigned short* __restrict__ wbf)
{
    int p = blockIdx.x * 256 + threadIdx.x;
    if (p < ON*CN*NT) {
        int o   = p / (CN*NT);
        int rem = p - o*(CN*NT);
        int c   = rem / NT;
        int n   = rem - c*NT;
        wbf[(n*ON + o)*CN + c] = f2bf(w_conv[p]);
    }
}

// ---------------------------------------------------------------------------
// Prep kernel: cooperative offset conv (64 px/block) -> homography -> 9
// relative offsets per pixel, written to global. Lean: ~5.5 KB LDS, low VGPR.
// ---------------------------------------------------------------------------
__global__ __launch_bounds__(256) void prep_offsets(
    const float* __restrict__ x, const float* __restrict__ w_off,
    const float* __restrict__ P, const float* __restrict__ d,
    const float* __restrict__ Pinv, float2* __restrict__ offs)
{
    __shared__ float swoff[CN*NT];      // 576
    __shared__ float partials[256];
    __shared__ float HomLDS[64*9];

    const int tid  = threadIdx.x;
    const int lane = tid & 63;
    const int g    = tid >> 6;

    // same swizzle as deform_kernel -> same block does same pixels (L2 locality)
    const int nb    = ((blockIdx.x & 7) << 7) | (blockIdx.x >> 3);
    const int pbase = nb * 64;
    const int w0    = pbase & (WN-1);
    const int hi    = (pbase >> 7) & (HN-1);
    const int bi    = pbase >> 14;
    const float* xb = x + (size_t)bi * CN * HWN;

    for (int i = tid; i < CN*NT; i += 256) swoff[i] = w_off[i];
    __syncthreads();

    // offset conv: lane = pixel, wave g = channels g*16..g*16+15
    {
        float part = 0.f;
        #pragma unroll
        for (int ky = 0; ky < 3; ++ky) {
            int yy = hi + ky - 1;
            bool vy = (yy >= 0) & (yy < HN);
            #pragma unroll
            for (int kx = 0; kx < 3; ++kx) {
                int xx = w0 + lane + kx - 1;
                bool v = vy & (xx >= 0) & (xx < WN);
                int a = yy*WN + xx;
                #pragma unroll
                for (int j = 0; j < 16; ++j) {
                    int c = g*16 + j;
                    float xv = v ? xb[c*HWN + a] : 0.f;
                    part += xv * swoff[c*NT + ky*3 + kx];
                }
            }
        }
        partials[g*64 + lane] = part;
    }
    __syncthreads();

    // per-pixel homography (threads 0..63)
    if (tid < 64) {
        float raw = partials[tid] + partials[64+tid] + partials[128+tid] + partials[192+tid];
        float lw = fminf(fmaxf(raw + 0.5f, 0.f), 1.f);
        float pw0 = exp2f(lw * log2f(d[0]));
        float pw1 = exp2f(lw * log2f(d[1]));
        float pw2 = exp2f(lw * log2f(d[2]));
        #pragma unroll
        for (int i = 0; i < 3; ++i)
            #pragma unroll
            for (int j = 0; j < 3; ++j)
                HomLDS[tid*9 + i*3 + j] = P[i*3+0]*pw0*Pinv[0+j]
                                        + P[i*3+1]*pw1*Pinv[3+j]
                                        + P[i*3+2]*pw2*Pinv[6+j];
    }
    __syncthreads();

    // relative offsets: sampling pos = (ix + qx/qz, iy + qy/qz)
    for (int e = tid; e < 64*NT; e += 256) {
        int pix = e / NT, n = e - pix*NT;
        const float* Hm = &HomLDS[pix*9];
        float fx0 = (float)(n % 3) - 1.f;
        float fy0 = (float)(n / 3) - 1.f;
        float qx = Hm[0]*fx0 + Hm[1]*fy0 + Hm[2];
        float qy = Hm[3]*fx0 + Hm[4]*fy0 + Hm[5];
        float qz = Hm[6]*fx0 + Hm[7]*fy0 + Hm[8];
        float ri = 1.f / qz;
        offs[(size_t)(pbase + pix)*NT + n] = make_float2(qx*ri, qy*ri);
    }
}

// ---------------------------------------------------------------------------
// Deform kernel (verified R1 structure + XCD swizzle): 64 px/block.
// Per tap: bilinear-gather a 64px x 64c bf16 tile into LDS, MFMA vs wbf.
// ---------------------------------------------------------------------------
#define LDS_BYTES 27648   // tapA 9216 | tapW 9216 | sT 9216 (64 x 72 bf16)

__global__ __launch_bounds__(256) void deform_kernel(
    const float* __restrict__ x, const float2* __restrict__ offs,
    const unsigned short* __restrict__ wbf, float* __restrict__ out)
{
    __shared__ char lds[LDS_BYTES];
    int4*   tapA = (int4*)lds;                              // [576]
    float4* tapW = (float4*)(lds + 9216);                   // [576]
    unsigned short* sT = (unsigned short*)(lds + 18432);    // [64][72]

    const int tid   = threadIdx.x;
    // XCD-contiguity swizzle: XCD k gets contiguous 128-block chunk (2.1 MB slab)
    const int nb    = ((blockIdx.x & 7) << 7) | (blockIdx.x >> 3);
    const int pbase = nb * 64;
    const int w0    = pbase & (WN-1);
    const int hi    = (pbase >> 7) & (HN-1);
    const int bi    = pbase >> 14;

    // ---- tap precompute: clamped corner addresses + validity-folded weights
    for (int e = tid; e < 64*NT; e += 256) {
        int pix = e / NT, n = e - pix*NT;
        float2 off = offs[(size_t)(pbase + pix)*NT + n];
        float px = (float)(w0 + pix) + off.x;
        float py = (float)hi + off.y;
        float x0f = floorf(px), y0f = floorf(py);
        float fx = px - x0f,    fy = py - y0f;
        int ix0 = (int)x0f, iy0 = (int)y0f;
        int ix1 = ix0 + 1,  iy1 = iy0 + 1;
        float vx0 = (ix0 >= 0 && ix0 < WN) ? 1.f : 0.f;
        float vx1 = (ix1 >= 0 && ix1 < WN) ? 1.f : 0.f;
        float vy0 = (iy0 >= 0 && iy0 < HN) ? 1.f : 0.f;
        float vy1 = (iy1 >= 0 && iy1 < HN) ? 1.f : 0.f;
        int x0c = min(max(ix0,0),WN-1), x1c = min(max(ix1,0),WN-1);
        int y0c = min(max(iy0,0),HN-1), y1c = min(max(iy1,0),HN-1);
        tapA[e] = make_int4(y0c*WN+x0c, y0c*WN+x1c, y1c*WN+x0c, y1c*WN+x1c);
        tapW[e] = make_float4((1.f-fy)*(1.f-fx)*vy0*vx0, (1.f-fy)*fx*vy0*vx1,
                              fy*(1.f-fx)*vy1*vx0,       fy*fx*vy1*vx1);
    }

    const int lane = tid & 63;
    const int g    = tid >> 6;           // wave id 0..3
    const int q    = lane >> 4;          // quad within wave
    const int m15  = lane & 15;
    const int mpix = g*16 + m15;         // this wave's pixel-tile rows
    const float* xb = x + (size_t)bi * CN * HWN;

    floatx4 acc[4];
    #pragma unroll
    for (int f = 0; f < 4; ++f) acc[f] = (floatx4){0.f,0.f,0.f,0.f};

    for (int n = 0; n < NT; ++n) {
        __syncthreads();                 // sT safe to overwrite / taps ready
        {
            // gather: lanes = pixels (coalesced), this wave covers c=g*16..+15
            int pix = lane;
            int4   ta = tapA[pix*NT + n];
            float4 tw = tapW[pix*NT + n];
            const float* pc = xb + (g*16)*HWN;
            unsigned int packed[8];
            #pragma unroll
            for (int jj = 0; jj < 8; ++jj) {
                const float* p0 = pc + (2*jj)*HWN;
                float v0 = tw.x*p0[ta.x] + tw.y*p0[ta.y]
                         + tw.z*p0[ta.z] + tw.w*p0[ta.w];
                const float* p1 = p0 + HWN;
                float v1 = tw.x*p1[ta.x] + tw.y*p1[ta.y]
                         + tw.z*p1[ta.z] + tw.w*p1[ta.w];
                packed[jj] = (unsigned int)f2bf(v0)
                           | ((unsigned int)f2bf(v1) << 16);
            }
            int4* dst = (int4*)&sT[pix*72 + g*16];   // 16B-aligned (72*2=144)
            dst[0] = make_int4(packed[0],packed[1],packed[2],packed[3]);
            dst[1] = make_int4(packed[4],packed[5],packed[6],packed[7]);
        }
        __syncthreads();

        // MFMA: wave g computes pix rows [g*16, g*16+16) x all 64 o
        #pragma unroll
        for (int k0 = 0; k0 < 64; k0 += 32) {
            bf16x8 a = *(const bf16x8*)&sT[mpix*72 + k0 + q*8];
            #pragma unroll
            for (int f = 0; f < 4; ++f) {
                bf16x8 bfr = *(const bf16x8*)&wbf[((size_t)(n*ON + f*16 + m15))*CN + k0 + q*8];
                acc[f] = __builtin_amdgcn_mfma_f32_16x16x32_bf16(a, bfr, acc[f], 0, 0, 0);
            }
        }
    }

    // ---- epilogue: transpose through LDS for coalesced stores
    __syncthreads();
    float* tr = (float*)lds;             // [64 o][72 pix], over tap region (dead)
    #pragma unroll
    for (int f = 0; f < 4; ++f) {
        int o = f*16 + m15;
        #pragma unroll
        for (int r = 0; r < 4; ++r) {
            int pix = g*16 + q*4 + r;    // C/D layout: row=(lane>>4)*4+reg
            tr[o*72 + pix] = acc[f][r];
        }
    }
    __syncthreads();
    float* ob = out + (((size_t)bi*ON)*HN + hi)*WN + w0;
    #pragma unroll
    for (int j = 0; j < 16; ++j) {
        int o = g*16 + j;
        ob[(size_t)o*HWN + lane] = tr[o*72 + lane];
    }
}

// ---------------------------------------------------------------------------
extern "C" void kernel_launch(void* const* d_in, const int* in_sizes, int n_in,
                              void* d_out, int out_size, void* d_ws, size_t ws_size,
                              hipStream_t stream) {
    const float* x      = (const float*)d_in[0];
    const float* w_off  = (const float*)d_in[1];
    const float* w_conv = (const float*)d_in[2];
    const float* P      = (const float*)d_in[3];
    const float* d      = (const float*)d_in[4];
    const float* Pinv   = (const float*)d_in[5];
    float* out = (float*)d_out;

    float2* offs = (float2*)d_ws;                                    // 4718592 B
    unsigned short* wbf = (unsigned short*)((char*)d_ws + 4718592);  // 73728 B

    prep_wbf<<<144, 256, 0, stream>>>(w_conv, wbf);
    prep_offsets<<<1024, 256, 0, stream>>>(x, w_off, P, d, Pinv, offs);
    deform_kernel<<<1024, 256, 0, stream>>>(x, offs, wbf, out);
}